// Round 1
// baseline (325.175 us; speedup 1.0000x reference)
//
#include <hip/hip_runtime.h>

#define C_DIM 256   // embedding dim (fixed by problem)

// ---------------- Kernel A: e_norm[j] = sum_k emb[j][k]^2 ----------------
// One wave (64 lanes) per code row; each lane loads one float4 (64*4 = 256).
__global__ __launch_bounds__(256) void enorm_kernel(const float* __restrict__ emb,
                                                    float* __restrict__ enorm,
                                                    int n_codes) {
    int gid  = blockIdx.x * blockDim.x + threadIdx.x;
    int wave = gid >> 6;
    int lane = gid & 63;
    if (wave >= n_codes) return;
    const float4 v = reinterpret_cast<const float4*>(emb)[(size_t)wave * 64 + lane];
    float s = v.x * v.x + v.y * v.y + v.z * v.z + v.w * v.w;
    #pragma unroll
    for (int off = 32; off; off >>= 1) s += __shfl_xor(s, off, 64);
    if (lane == 0) enorm[wave] = s;
}

// ---------------- Kernel B: distances + argmin + gather ----------------
// 64 rows per workgroup. Loop 16 code-blocks of 64 codes; each block: 4
// K-chunks of 64 dims staged in LDS (+4 pad -> <=2-way bank aliasing, free).
// Thread (tx=t&15, ty=t>>4): rows ty*4..+3, codes {tx + 16*cc} within block.
// dist = e_norm[c] - 2 * (z . e)   (||z||^2 dropped: constant per row)
#define DOT4(A, B, ACC)                      \
    ACC = fmaf((A).x, (B).x, ACC);           \
    ACC = fmaf((A).y, (B).y, ACC);           \
    ACC = fmaf((A).z, (B).z, ACC);           \
    ACC = fmaf((A).w, (B).w, ACC);

__global__ __launch_bounds__(256, 2) void vq_kernel(
    const float* __restrict__ z, const float* __restrict__ emb,
    const float* __restrict__ enorm, float* __restrict__ zq,
    float* __restrict__ idx_out) {
    __shared__ float zt[64][68];       // 17.4 KB  (pad +4: bank stride 4)
    __shared__ float et[64][68];       // 17.4 KB
    __shared__ float enorm_s[1024];    // 4 KB
    __shared__ float rv[64][16];       // 4 KB reduction values
    __shared__ int   ri[64][16];       // 4 KB reduction indices
    __shared__ int   ridx[64];         // final index per row

    const int  t    = threadIdx.x;
    const int  tx   = t & 15;
    const int  ty   = t >> 4;
    const long row0 = (long)blockIdx.x * 64;

    for (int i = t; i < 1024; i += 256) enorm_s[i] = enorm[i];
    // (enorm_s consumed only after several __syncthreads below)

    float best[4];
    int   bidx[4];
    #pragma unroll
    for (int r = 0; r < 4; ++r) { best[r] = 3.4e38f; bidx[r] = 0; }

    const int ldr = t >> 4;   // staging row base (0..15)
    const int ldc = t & 15;   // staging float4 column (0..15)

    for (int cb = 0; cb < 16; ++cb) {
        float acc[4][4];
        #pragma unroll
        for (int a = 0; a < 4; ++a)
            #pragma unroll
            for (int b = 0; b < 4; ++b) acc[a][b] = 0.f;

        for (int kc = 0; kc < 4; ++kc) {
            __syncthreads();   // previous iteration's reads done
            #pragma unroll
            for (int i = 0; i < 4; ++i) {
                int rr = ldr + 16 * i;
                float4 v = *reinterpret_cast<const float4*>(
                    z + (row0 + rr) * C_DIM + kc * 64 + ldc * 4);
                *reinterpret_cast<float4*>(&zt[rr][ldc * 4]) = v;
                float4 w = *reinterpret_cast<const float4*>(
                    emb + (long)(cb * 64 + rr) * C_DIM + kc * 64 + ldc * 4);
                *reinterpret_cast<float4*>(&et[rr][ldc * 4]) = w;
            }
            __syncthreads();

            #pragma unroll
            for (int k4 = 0; k4 < 16; ++k4) {
                float4 a0 = *reinterpret_cast<const float4*>(&zt[ty * 4 + 0][k4 * 4]);
                float4 a1 = *reinterpret_cast<const float4*>(&zt[ty * 4 + 1][k4 * 4]);
                float4 a2 = *reinterpret_cast<const float4*>(&zt[ty * 4 + 2][k4 * 4]);
                float4 a3 = *reinterpret_cast<const float4*>(&zt[ty * 4 + 3][k4 * 4]);
                float4 b0 = *reinterpret_cast<const float4*>(&et[tx +  0][k4 * 4]);
                float4 b1 = *reinterpret_cast<const float4*>(&et[tx + 16][k4 * 4]);
                float4 b2 = *reinterpret_cast<const float4*>(&et[tx + 32][k4 * 4]);
                float4 b3 = *reinterpret_cast<const float4*>(&et[tx + 48][k4 * 4]);
                DOT4(a0, b0, acc[0][0]); DOT4(a0, b1, acc[0][1]);
                DOT4(a0, b2, acc[0][2]); DOT4(a0, b3, acc[0][3]);
                DOT4(a1, b0, acc[1][0]); DOT4(a1, b1, acc[1][1]);
                DOT4(a1, b2, acc[1][2]); DOT4(a1, b3, acc[1][3]);
                DOT4(a2, b0, acc[2][0]); DOT4(a2, b1, acc[2][1]);
                DOT4(a2, b2, acc[2][2]); DOT4(a2, b3, acc[2][3]);
                DOT4(a3, b0, acc[3][0]); DOT4(a3, b1, acc[3][1]);
                DOT4(a3, b2, acc[3][2]); DOT4(a3, b3, acc[3][3]);
            }
        }

        // fold this code block into the running per-row argmin
        #pragma unroll
        for (int cc = 0; cc < 4; ++cc) {
            int   cg = cb * 64 + tx + 16 * cc;
            float en = enorm_s[cg];
            #pragma unroll
            for (int rr = 0; rr < 4; ++rr) {
                float d = fmaf(-2.f, acc[rr][cc], en);
                // per-thread code indices are visited in increasing order,
                // so strict < implements first-index tie-break
                if (d < best[rr]) { best[rr] = d; bidx[rr] = cg; }
            }
        }
    }

    // cross-thread (tx) reduction per row
    #pragma unroll
    for (int rr = 0; rr < 4; ++rr) {
        rv[ty * 4 + rr][tx] = best[rr];
        ri[ty * 4 + rr][tx] = bidx[rr];
    }
    __syncthreads();
    if (t < 64) {
        float bv = rv[t][0];
        int   bi = ri[t][0];
        #pragma unroll
        for (int j = 1; j < 16; ++j) {
            float v  = rv[t][j];
            int   i2 = ri[t][j];
            if (v < bv || (v == bv && i2 < bi)) { bv = v; bi = i2; }
        }
        ridx[t] = bi;
        idx_out[row0 + t] = (float)bi;   // indices as float32 (single-dtype d_out)
    }
    __syncthreads();

    // gather z_q rows from emb (L2-resident, 1 MB)
    {
        #pragma unroll
        for (int i = 0; i < 4; ++i) {
            int rr   = ldr + 16 * i;
            int code = ridx[rr];
            #pragma unroll
            for (int j = 0; j < 4; ++j) {
                int col = (ldc + 16 * j) * 4;
                float4 v = *reinterpret_cast<const float4*>(
                    emb + (long)code * C_DIM + col);
                *reinterpret_cast<float4*>(zq + (row0 + rr) * C_DIM + col) = v;
            }
        }
    }
}

extern "C" void kernel_launch(void* const* d_in, const int* in_sizes, int n_in,
                              void* d_out, int out_size, void* d_ws, size_t ws_size,
                              hipStream_t stream) {
    const float* z   = (const float*)d_in[0];
    const float* emb = (const float*)d_in[1];
    const int n       = in_sizes[0] / C_DIM;   // 32768 rows
    const int n_codes = in_sizes[1] / C_DIM;   // 1024 codes

    float* zq      = (float*)d_out;
    float* idx_out = zq + (size_t)n * C_DIM;   // second output segment
    float* enorm   = (float*)d_ws;             // 4 KB scratch

    enorm_kernel<<<(n_codes * 64 + 255) / 256, 256, 0, stream>>>(emb, enorm, n_codes);
    vq_kernel<<<n / 64, 256, 0, stream>>>(z, emb, enorm, zq, idx_out);
}

// Round 2
// 305.283 us; speedup vs baseline: 1.0652x; 1.0652x over previous
//
#include <hip/hip_runtime.h>

#define C_DIM 256    // embedding dim
#define NCODE 1024   // codebook size
#define BM 128       // rows per block tile
#define BN 128       // codes per block tile
#define BK 32        // k-chunk staged in LDS
#define LDP 36       // padded LDS row stride (floats): bank-start = 4*row mod 32

// ws layout: [0,4KB) enorm f32[1024]; [4KB, 4KB+256KB) best u64[32768]
#define WS_BEST_OFF 4096

// sortable-uint transform: u64 key = (fkey(dist)<<32)|idx; min == lexicographic
__device__ __forceinline__ unsigned int fkey(float f) {
    unsigned int u = __float_as_uint(f);
    return (u & 0x80000000u) ? ~u : (u | 0x80000000u);
}

// ---------- Kernel A: e-norms + init best keys ----------
__global__ __launch_bounds__(256) void prep_kernel(const float* __restrict__ emb,
                                                   float* __restrict__ enorm,
                                                   unsigned long long* __restrict__ best,
                                                   int n_codes, int n_rows) {
    int gid  = blockIdx.x * blockDim.x + threadIdx.x;
    int wave = gid >> 6;
    int lane = gid & 63;
    if (gid < n_rows) best[gid] = 0xFFFFFFFFFFFFFFFFull;
    if (wave < n_codes) {
        const float4 v = reinterpret_cast<const float4*>(emb)[(size_t)wave * 64 + lane];
        float s = v.x * v.x + v.y * v.y + v.z * v.z + v.w * v.w;
        #pragma unroll
        for (int off = 32; off; off >>= 1) s += __shfl_xor(s, off, 64);
        if (lane == 0) enorm[wave] = s;
    }
}

// ---------- Kernel B: partial distances + per-block argmin ----------
#define DOT4(A, B, ACC)                      \
    ACC = fmaf((A).x, (B).x, ACC);           \
    ACC = fmaf((A).y, (B).y, ACC);           \
    ACC = fmaf((A).z, (B).z, ACC);           \
    ACC = fmaf((A).w, (B).w, ACC);

__global__ __launch_bounds__(256, 2) void vq_partial_kernel(
    const float* __restrict__ z, const float* __restrict__ emb,
    const float* __restrict__ enorm, unsigned long long* __restrict__ best) {
    __shared__ float at_[BM * LDP];     // 18.4 KB
    __shared__ float bt_[BN * LDP];     // 18.4 KB
    __shared__ float enorm_s[BN];       // 512 B

    const int t  = threadIdx.x;
    const int tx = t & 15;
    const int ty = t >> 4;
    const long r0 = (long)blockIdx.x * BM;   // row-tile base
    const int  c0 = blockIdx.y * BN;         // code-tile base

    if (t < BN) enorm_s[t] = enorm[c0 + t];

    float acc[8][8];
    #pragma unroll
    for (int r = 0; r < 8; ++r)
        #pragma unroll
        for (int c = 0; c < 8; ++c) acc[r][c] = 0.f;

    for (int kc = 0; kc < C_DIM / BK; ++kc) {
        __syncthreads();   // previous iter's reads done (and enorm_s ready)
        // stage A and B tiles: 1024 float4 each, 4 per thread
        #pragma unroll
        for (int i = 0; i < 4; ++i) {
            int id   = t + 256 * i;
            int srow = id >> 3;        // 0..127
            int sc4  = id & 7;         // 0..7
            float4 va = *reinterpret_cast<const float4*>(
                z + (r0 + srow) * C_DIM + kc * BK + sc4 * 4);
            *reinterpret_cast<float4*>(&at_[srow * LDP + sc4 * 4]) = va;
            float4 vb = *reinterpret_cast<const float4*>(
                emb + (long)(c0 + srow) * C_DIM + kc * BK + sc4 * 4);
            *reinterpret_cast<float4*>(&bt_[srow * LDP + sc4 * 4]) = vb;
        }
        __syncthreads();

        #pragma unroll 4
        for (int k4 = 0; k4 < BK / 4; ++k4) {
            float4 a[8], b[8];
            #pragma unroll
            for (int r = 0; r < 8; ++r)
                a[r] = *reinterpret_cast<const float4*>(&at_[(ty + 16 * r) * LDP + k4 * 4]);
            #pragma unroll
            for (int c = 0; c < 8; ++c)
                b[c] = *reinterpret_cast<const float4*>(&bt_[(tx + 16 * c) * LDP + k4 * 4]);
            #pragma unroll
            for (int r = 0; r < 8; ++r)
                #pragma unroll
                for (int c = 0; c < 8; ++c) { DOT4(a[r], b[c], acc[r][c]); }
        }
    }

    // per-thread argmin over its 8 cols, per row
    float bv[8];
    int   bi[8];
    #pragma unroll
    for (int r = 0; r < 8; ++r) {
        bv[r] = 3.4e38f; bi[r] = 0;
        #pragma unroll
        for (int c = 0; c < 8; ++c) {
            int   cl = tx + 16 * c;                      // ascending in c
            float d  = fmaf(-2.f, acc[r][c], enorm_s[cl]);
            if (d < bv[r]) { bv[r] = d; bi[r] = c0 + cl; }
        }
    }

    // cross-tx reduction via LDS (reuse at_ buffer)
    __syncthreads();
    float* rv = at_;                       // [128][16] floats
    int*   ri = reinterpret_cast<int*>(bt_);  // [128][16] ints
    #pragma unroll
    for (int r = 0; r < 8; ++r) {
        int row = ty + 16 * r;
        rv[row * 16 + tx] = bv[r];
        ri[row * 16 + tx] = bi[r];
    }
    __syncthreads();
    if (t < BM) {
        float v = rv[t * 16];
        int   i = ri[t * 16];
        #pragma unroll
        for (int j = 1; j < 16; ++j) {
            float v2 = rv[t * 16 + j];
            int   i2 = ri[t * 16 + j];
            if (v2 < v || (v2 == v && i2 < i)) { v = v2; i = i2; }
        }
        unsigned long long key =
            ((unsigned long long)fkey(v) << 32) | (unsigned int)i;
        atomicMin(&best[r0 + t], key);
    }
}

// ---------- Kernel C: finalize — write indices + gather z_q ----------
__global__ __launch_bounds__(256) void finalize_kernel(
    const float* __restrict__ emb, const unsigned long long* __restrict__ best,
    float* __restrict__ zq, float* __restrict__ idx_out) {
    const int t    = threadIdx.x;
    const long row = (long)blockIdx.x * 4 + (t >> 6);
    const int lane = t & 63;
    unsigned long long k = best[row];
    unsigned int idx = (unsigned int)(k & 0xFFFFFFFFu);
    float4 v = reinterpret_cast<const float4*>(emb)[(size_t)idx * 64 + lane];
    reinterpret_cast<float4*>(zq)[row * 64 + lane] = v;
    if (lane == 0) idx_out[row] = (float)idx;
}

extern "C" void kernel_launch(void* const* d_in, const int* in_sizes, int n_in,
                              void* d_out, int out_size, void* d_ws, size_t ws_size,
                              hipStream_t stream) {
    const float* z   = (const float*)d_in[0];
    const float* emb = (const float*)d_in[1];
    const int n       = in_sizes[0] / C_DIM;   // 32768
    const int n_codes = in_sizes[1] / C_DIM;   // 1024

    float* zq      = (float*)d_out;
    float* idx_out = zq + (size_t)n * C_DIM;
    float* enorm   = (float*)d_ws;
    unsigned long long* best =
        (unsigned long long*)((char*)d_ws + WS_BEST_OFF);

    prep_kernel<<<(n_codes * 64 + 255) / 256, 256, 0, stream>>>(emb, enorm, best,
                                                                n_codes, n);
    dim3 grid(n / BM, n_codes / BN);
    vq_partial_kernel<<<grid, 256, 0, stream>>>(z, emb, enorm, best);
    finalize_kernel<<<n / 4, 256, 0, stream>>>(emb, best, zq, idx_out);
}